// Round 3
// baseline (304.901 us; speedup 1.0000x reference)
//
#include <hip/hip_runtime.h>
#include <stdint.h>

typedef __attribute__((ext_vector_type(8))) short short8;
typedef __attribute__((ext_vector_type(4))) float f32x4;

__device__ __forceinline__ unsigned short f32_to_bf16(float f) {
    unsigned int u = __float_as_uint(f);
    u += 0x7FFFu + ((u >> 16) & 1u);   // round-to-nearest-even
    return (unsigned short)(u >> 16);
}

__device__ __forceinline__ short8 load8_f32_as_bf16(const float* __restrict__ ap) {
    f32x4 f0 = *(const f32x4*)ap;
    f32x4 f1 = *(const f32x4*)(ap + 4);
    union { short8 s; unsigned short u[8]; } cv;
#pragma unroll
    for (int t = 0; t < 4; ++t) {
        cv.u[t]     = f32_to_bf16(f0[t]);
        cv.u[t + 4] = f32_to_bf16(f1[t]);
    }
    return cv.s;
}

// async global->LDS DMA, 16B/lane; LDS dest = wave-uniform base + lane*16 (m104/m108)
__device__ __forceinline__ void gld_lds16(const void* g, void* l) {
    __builtin_amdgcn_global_load_lds(
        (const __attribute__((address_space(1))) unsigned int*)(unsigned long long)(uintptr_t)g,
        (__attribute__((address_space(3))) unsigned int*)(unsigned int)(uintptr_t)l,
        16, 0, 0);
}

// cumulative count of 128-wide n-blocks for 64-row causal m-tiles 0..y-1
__device__ __forceinline__ int triC(int y) {
    int t = y >> 1;
    return y + t * (t - 1) + ((y & 1) ? t : 0);
}

// ---------------------------------------------------------------------------
// Old NT GEMM template (kept for the triangular attention launches: scores
// EPI=6 and PV EPI=4). Single-buffer 2-barrier per K-tile, MT x 128 tile,
// 4 waves. Swizzle chunk' = c ^ (row&7): SQ_LDS_BANK_CONFLICT == 0 (R4).
// ---------------------------------------------------------------------------
template<int AMODE, int EPI, int SWIZ, bool KLIMIT, int MT>
__global__ __launch_bounds__(256, 4)
void gemm128(const unsigned short* __restrict__ A, const unsigned short* __restrict__ A2,
             int lda, int lda2, int ksplit,
             const unsigned short* __restrict__ B, int ldb,
             void* __restrict__ C, int ldc, int K,
             long aStride, long bStride, long cStride,
             const float* __restrict__ bias, long biasStride, float scale,
             void* __restrict__ C2, int ldc2)
{
    int z = blockIdx.z;
    int mblk, nblk;
    if (SWIZ == 1) {
        int lin = blockIdx.y * gridDim.x + blockIdx.x;
        int mchunk = gridDim.y >> 3;
        int xcd = lin & 7, idx = lin >> 3;
        mblk = xcd * mchunk + idx % mchunk;   // m fast within XCD's chunk
        nblk = idx / mchunk;                  // n slow
    } else if (SWIZ == 4) {
        mblk = (z & 2) ? ((int)gridDim.y - 1 - (int)blockIdx.y) : blockIdx.y;
        nblk = blockIdx.x;
    } else if (SWIZ == 5) {
        int x = blockIdx.x;
        int a = (int)(2.f * sqrtf((float)x));
        if (a > 31) a = 31;
        while (a < 31 && triC(a + 1) <= x) ++a;
        while (a > 0 && triC(a) > x) --a;
        mblk = a;
        nblk = x - triC(a);
    } else {
        mblk = blockIdx.y;
        nblk = blockIdx.x;
    }
    int m0 = mblk * MT;
    int n0 = nblk * 128;

    const unsigned short* Ab = A + (size_t)z * aStride;
    const unsigned short* Bb = B + (size_t)z * bStride;

    __shared__ __align__(16) short As[MT * 64];
    __shared__ __align__(16) short Bs[128 * 64];

    int tid  = threadIdx.x;
    int lane = tid & 63, wid = tid >> 6;
    constexpr int MI = MT / 32;              // a-frag / acc-row count per wave
    int wm = (wid & 1) * (MT / 2), wn = (wid >> 1) * 64;
    int fr = lane & 15, fq = lane >> 4;
    int sw0 = ((fq    ) ^ (fr & 7)) * 16;
    int sw1 = ((fq ^ 4) ^ (fr & 7)) * 16;

    int rS = tid >> 3;
    int cS = ((tid & 7) ^ (rS & 7)) * 8;   // element offset in k
    char* AsB = (char*)As; char* BsB = (char*)Bs;

    int kend = KLIMIT ? min(K, m0 + MT) : K;

    f32x4 acc[MI][4];
#pragma unroll
    for (int i = 0; i < MI; ++i)
#pragma unroll
    for (int j = 0; j < 4; ++j) acc[i][j] = f32x4{0.f, 0.f, 0.f, 0.f};

    for (int k0 = 0; k0 < kend; k0 += 64) {
        const unsigned short* Asrc = Ab;
        int koff = k0, ldax = lda;
        if (AMODE == 2 && k0 >= ksplit) { Asrc = A2; koff = k0 - ksplit; ldax = lda2; }
        const unsigned short* pa = Asrc + (size_t)(m0 + rS) * ldax + koff + cS;
        const unsigned short* pb = Bb   + (size_t)(n0 + rS) * ldb  + k0   + cS;
#pragma unroll
        for (int t = 0; t < MT / 32; ++t)
            gld_lds16(pa + (size_t)(32 * t) * ldax, AsB + t * 4096 + tid * 16);
#pragma unroll
        for (int t = 0; t < 4; ++t)
            gld_lds16(pb + (size_t)(32 * t) * ldb,  BsB + t * 4096 + tid * 16);
        __syncthreads();

#pragma unroll
        for (int kh = 0; kh < 2; ++kh) {
            int sw = kh ? sw1 : sw0;
            short8 a[MI], b[4];
#pragma unroll
            for (int i = 0; i < MI; ++i)
                a[i] = *(const short8*)(AsB + (wm + i * 16 + fr) * 128 + sw);
#pragma unroll
            for (int j = 0; j < 4; ++j)
                b[j] = *(const short8*)(BsB + (wn + j * 16 + fr) * 128 + sw);
#pragma unroll
            for (int i = 0; i < MI; ++i)
#pragma unroll
            for (int j = 0; j < 4; ++j)
                acc[i][j] = __builtin_amdgcn_mfma_f32_16x16x32_bf16(a[i], b[j], acc[i][j], 0, 0, 0);
        }
        __syncthreads();
    }

    // epilogue: C/D layout col = lane&15, row = (lane>>4)*4 + reg [m89/m91]
    if (EPI == 6) {
        unsigned short* Cz = (unsigned short*)C + (size_t)z * cStride;
        float* rs = const_cast<float*>(bias) + z * biasStride;
#pragma unroll
        for (int i = 0; i < MI; ++i)
#pragma unroll
        for (int r = 0; r < 4; ++r) {
            int row = m0 + wm + i * 16 + fq * 4 + r;
            float s = 0.f;
#pragma unroll
            for (int j = 0; j < 4; ++j) {
                int col = n0 + wn + j * 16 + fr;
                float e = (col <= row) ? __expf(acc[i][j][r] * scale - 16.f) : 0.f;
                s += e;
                Cz[(size_t)row * ldc + col] = f32_to_bf16(e);
            }
            s += __shfl_xor(s, 1);
            s += __shfl_xor(s, 2);
            s += __shfl_xor(s, 4);
            s += __shfl_xor(s, 8);      // reduced over the 16 fr-lanes
            if (fr == 0) atomicAdd(&rs[row], s);
        }
    } else if (EPI == 4) {
        unsigned short* Cz = (unsigned short*)C + (size_t)z * cStride;
#pragma unroll
        for (int i = 0; i < MI; ++i)
#pragma unroll
        for (int r = 0; r < 4; ++r) {
            int row = m0 + wm + i * 16 + fq * 4 + r;
            float inv = 1.f / bias[z * biasStride + row];
#pragma unroll
            for (int j = 0; j < 4; ++j) {
                int col = n0 + wn + j * 16 + fr;
                Cz[(size_t)row * ldc + col] = f32_to_bf16(acc[i][j][r] * inv);
            }
        }
    } else {   // EPI == 0: bf16 store
        unsigned short* Cz = (unsigned short*)C + (size_t)z * cStride;
#pragma unroll
        for (int i = 0; i < MI; ++i)
#pragma unroll
        for (int j = 0; j < 4; ++j)
#pragma unroll
        for (int r = 0; r < 4; ++r) {
            int row = m0 + wm + i * 16 + fq * 4 + r;
            int col = n0 + wn + j * 16 + fr;
            Cz[(size_t)row * ldc + col] = f32_to_bf16(acc[i][j][r]);
        }
    }
}

// ---------------------------------------------------------------------------
// gemm2p: fine-grained 2-phase deep-pipelined NT GEMM (T2+T3+T4+T5).
// C[M,N] = A[M,K]*B[N,K]^T. BM=256 x BN=128, BK=64 split as two ks=32 halves,
// 512 threads = 8 waves (4M x 2N, 64x64/wave, acc 4x4 = 64 VGPR).
// LDS 96 KB: A regions (d*2+s)*16KB in [0,64K), B regions 65536+(d*2+s)*8K.
// Per phase (= one ks half): {8 ds_read_b128, stage 1 A-HT(2 gld)+1 B-HT(1
// gld)} -> s_barrier -> lgkmcnt(0)+sched_barrier -> setprio(1) 16 MFMA
// setprio(0) -> counted vmcnt gate -> s_barrier. Per-wave lgkmcnt release is
// staggered -> one wave's MFMA overlaps another's LDS drain (m198/m201
// mechanism); gates never drain to 0 until the final K-tile.
// Stage schedule: kt t ph0 stages (t+1, ks1); ph1 stages (t+2, ks0).
// Slack = 3 phases for every HT. Gate ledger (2 A-loads + 1 B-load per HT):
//   ph0-end: need (t,ks1) [staged t-1 ph0]; issued-after = t-1 ph1 + t ph0
//            = 6 loads -> vmcnt(6); t==NT-1 -> vmcnt(0) (final drain).
//   ph1-end: need (t+1,ks0) [staged t-1 ph1]; issued-after = t ph0 + t ph1
//            = 6 -> vmcnt(6); t==NT-2 -> 3 (t ph1 guarded out); t==NT-1 none.
// WAR: region staged at ph_x was fully consumed (lgkmcnt before MFMA) prior
// to the preceding closing barrier in all cases (audited).
// LDS swizzle for 64B rows: chunk' = c ^ ((row>>1)&3) -> uniform 2-way bank
// aliasing (free, m136); read-side term is lane-constant ((fr>>1)&3).
// SWIZ: 1 = XCD m-chunk (gridDim.y % 8 == 0); 2 = XCD n-chunk (gridDim.x
// % 8 == 0, for vT so each XCD re-reads its xb n-chunk).
// EPI: 0 bf16 | 2 relu(+bias[col]) bf16 | 3 +bias[col] fp32.
// AMODE 2: A switches to A2 at k>=ksplit (MLP1 concat; ksplit % 64 == 0).
// Requires NT >= 3 (all call sites NT >= 16), N % 128 == 0, M % 256 == 0.
// ---------------------------------------------------------------------------
template<int AMODE, int EPI, int SWIZ>
__global__ __launch_bounds__(512, 2)
void gemm2p(const unsigned short* __restrict__ A, const unsigned short* __restrict__ A2,
            int lda, int lda2, int ksplit,
            const unsigned short* __restrict__ B, int ldb,
            void* __restrict__ C, int ldc, int K,
            long bStride, long cStride,
            const float* __restrict__ bias)
{
    int z = blockIdx.z;
    int lin = blockIdx.y * gridDim.x + blockIdx.x;
    int xcd = lin & 7, idx = lin >> 3;
    int mblk, nblk;
    if (SWIZ == 2) {
        int nch = (int)gridDim.x >> 3;
        nblk = xcd * nch + idx % nch;
        mblk = idx / nch;
    } else {
        int mch = (int)gridDim.y >> 3;
        mblk = xcd * mch + idx % mch;
        nblk = idx / mch;
    }
    int m0 = mblk * 256, n0 = nblk * 128;

    const unsigned short* Bb = B + (size_t)z * bStride;

    __shared__ __align__(16) char lds[98304];

    int tid  = threadIdx.x;
    int lane = tid & 63, wid = tid >> 6;
    int wm = (wid & 3) * 64, wn = (wid >> 2) * 64;
    int fr = lane & 15, fq = lane >> 4;
    int swA = (fq ^ ((fr >> 1) & 3)) * 16;   // lane-constant read swizzle

    // staging: thread t covers row (tid>>2) (+128 for A's 2nd load), dst
    // chunk cI = tid&3; source chunk = cI ^ ((row>>1)&3) = cI ^ ((tid>>3)&3)
    int rS  = tid >> 2;                      // 0..127
    int cSw = ((tid & 3) ^ ((tid >> 3) & 3)) * 8;   // element offset in k

    int NT = K >> 6;

    f32x4 acc[4][4];
#pragma unroll
    for (int i = 0; i < 4; ++i)
#pragma unroll
    for (int j = 0; j < 4; ++j) acc[i][j] = f32x4{0.f, 0.f, 0.f, 0.f};

    auto STAGE_A = [&](int kt, int s) {      // 16 KB half-tile, 2 gld_lds
        if (kt >= NT) return;
        char* dst = lds + (((kt & 1) * 2 + s) * 16384) + tid * 16;
        const unsigned short* Asrc = A; int koff = kt << 6; int ldax = lda;
        if (AMODE == 2 && koff >= ksplit) { Asrc = A2; koff -= ksplit; ldax = lda2; }
        const unsigned short* pa = Asrc + (size_t)(m0 + rS) * ldax + koff + (s << 5) + cSw;
        gld_lds16(pa, dst);
        gld_lds16(pa + (size_t)128 * ldax, dst + 8192);
    };
    auto STAGE_B = [&](int kt, int s) {      // 8 KB half-tile, 1 gld_lds
        if (kt >= NT) return;
        char* dst = lds + 65536 + (((kt & 1) * 2 + s) * 8192) + tid * 16;
        const unsigned short* pb = Bb + (size_t)(n0 + rS) * ldb + (kt << 6) + (s << 5) + cSw;
        gld_lds16(pb, dst);
    };

    const char* Abase = lds + (wm + fr) * 64 + swA;
    const char* Bbase = lds + 65536 + (wn + fr) * 64 + swA;

    // prologue: (0,A0)(0,B0)(0,A1)(0,B1)(1,A0)(1,B0) = 9 loads; vmcnt(6)
    // leaves the 6 newest in flight -> (0,ks0) landed for kt0 ph0.
    STAGE_A(0, 0); STAGE_B(0, 0);
    STAGE_A(0, 1); STAGE_B(0, 1);
    STAGE_A(1, 0); STAGE_B(1, 0);
    asm volatile("s_waitcnt vmcnt(6)" ::: "memory");
    __builtin_amdgcn_s_barrier();
    asm volatile("" ::: "memory");
    __builtin_amdgcn_sched_barrier(0);

    for (int t = 0; t < NT; ++t) {
        int d2 = (t & 1) * 2;
        short8 a[4], b[4];
        // ---------------- phase 0 (ks = 0) ----------------
#pragma unroll
        for (int i = 0; i < 4; ++i) a[i] = *(const short8*)(Abase + (d2 + 0) * 16384 + i * 1024);
#pragma unroll
        for (int j = 0; j < 4; ++j) b[j] = *(const short8*)(Bbase + (d2 + 0) * 8192 + j * 1024);
        STAGE_A(t + 1, 1); STAGE_B(t + 1, 1);
        __builtin_amdgcn_s_barrier();
        asm volatile("s_waitcnt lgkmcnt(0)" ::: "memory");
        __builtin_amdgcn_sched_barrier(0);
        __builtin_amdgcn_s_setprio(1);
#pragma unroll
        for (int i = 0; i < 4; ++i)
#pragma unroll
        for (int j = 0; j < 4; ++j)
            acc[i][j] = __builtin_amdgcn_mfma_f32_16x16x32_bf16(a[i], b[j], acc[i][j], 0, 0, 0);
        __builtin_amdgcn_s_setprio(0);
        if (t == NT - 1) { asm volatile("s_waitcnt vmcnt(0)" ::: "memory"); }
        else             { asm volatile("s_waitcnt vmcnt(6)" ::: "memory"); }
        __builtin_amdgcn_s_barrier();
        asm volatile("" ::: "memory");
        __builtin_amdgcn_sched_barrier(0);
        // ---------------- phase 1 (ks = 1) ----------------
#pragma unroll
        for (int i = 0; i < 4; ++i) a[i] = *(const short8*)(Abase + (d2 + 1) * 16384 + i * 1024);
#pragma unroll
        for (int j = 0; j < 4; ++j) b[j] = *(const short8*)(Bbase + (d2 + 1) * 8192 + j * 1024);
        STAGE_A(t + 2, 0); STAGE_B(t + 2, 0);
        __builtin_amdgcn_s_barrier();
        asm volatile("s_waitcnt lgkmcnt(0)" ::: "memory");
        __builtin_amdgcn_sched_barrier(0);
        __builtin_amdgcn_s_setprio(1);
#pragma unroll
        for (int i = 0; i < 4; ++i)
#pragma unroll
        for (int j = 0; j < 4; ++j)
            acc[i][j] = __builtin_amdgcn_mfma_f32_16x16x32_bf16(a[i], b[j], acc[i][j], 0, 0, 0);
        __builtin_amdgcn_s_setprio(0);
        if (t < NT - 1) {
            if (t == NT - 2) { asm volatile("s_waitcnt vmcnt(3)" ::: "memory"); }
            else             { asm volatile("s_waitcnt vmcnt(6)" ::: "memory"); }
            __builtin_amdgcn_s_barrier();
            asm volatile("" ::: "memory");
            __builtin_amdgcn_sched_barrier(0);
        }
    }

    // epilogue: C/D layout col = lane&15, row = (lane>>4)*4 + reg [m89/m91]
    if (EPI == 0) {
        unsigned short* Cz = (unsigned short*)C + (size_t)z * cStride;
#pragma unroll
        for (int i = 0; i < 4; ++i)
#pragma unroll
        for (int j = 0; j < 4; ++j)
#pragma unroll
        for (int r = 0; r < 4; ++r) {
            int row = m0 + wm + i * 16 + fq * 4 + r;
            int col = n0 + wn + j * 16 + fr;
            Cz[(size_t)row * ldc + col] = f32_to_bf16(acc[i][j][r]);
        }
    } else if (EPI == 2) {
        unsigned short* Cz = (unsigned short*)C;
#pragma unroll
        for (int i = 0; i < 4; ++i)
#pragma unroll
        for (int j = 0; j < 4; ++j)
#pragma unroll
        for (int r = 0; r < 4; ++r) {
            int row = m0 + wm + i * 16 + fq * 4 + r;
            int col = n0 + wn + j * 16 + fr;
            float v = acc[i][j][r] + bias[col];
            v = v > 0.f ? v : 0.f;
            Cz[(size_t)row * ldc + col] = f32_to_bf16(v);
        }
    } else {   // EPI == 3: fp32 + bias
        float* Cz = (float*)C;
#pragma unroll
        for (int i = 0; i < 4; ++i)
#pragma unroll
        for (int j = 0; j < 4; ++j)
#pragma unroll
        for (int r = 0; r < 4; ++r) {
            int row = m0 + wm + i * 16 + fq * 4 + r;
            int col = n0 + wn + j * 16 + fr;
            Cz[(size_t)row * ldc + col] = acc[i][j][r] + bias[col];
        }
    }
}

// ---------------------------------------------------------------------------
// one prep launch: xb = bf16(x); WT = [Wq;Wk;Wv]^T; W1T; W2T; rsum = 0.
// ---------------------------------------------------------------------------
__device__ __forceinline__ void transpose_tile32(const float* __restrict__ in,
                                                 unsigned short* __restrict__ out,
                                                 int rows, int cols, int bx, int by, int tid)
{
    __shared__ float t[32][33];
    int tx = tid & 31, ty = tid >> 5;   // 32 x 8
    int r0 = by * 32, c0 = bx * 32;
#pragma unroll
    for (int i = 0; i < 4; ++i)
        t[ty + i * 8][tx] = in[(size_t)(r0 + ty + i * 8) * cols + c0 + tx];
    __syncthreads();
#pragma unroll
    for (int i = 0; i < 4; ++i)
        out[(size_t)(c0 + ty + i * 8) * rows + r0 + tx] = f32_to_bf16(t[tx][ty + i * 8]);
}

__global__ __launch_bounds__(256)
void prep_kernel(const float* __restrict__ x,
                 const float* __restrict__ Wq, const float* __restrict__ Wk,
                 const float* __restrict__ Wv, const float* __restrict__ W1,
                 const float* __restrict__ W2,
                 unsigned short* __restrict__ xb, unsigned short* __restrict__ WT,
                 unsigned short* __restrict__ W1T, unsigned short* __restrict__ W2T,
                 float* __restrict__ rsum)
{
    int idx = blockIdx.x;
    int tid = threadIdx.x;
    if (idx < 4096) {
        size_t i = ((size_t)idx * 256 + tid) * 8;
        *(short8*)(xb + i) = load8_f32_as_bf16(x + i);
    } else if (idx < 7168) {
        int t = idx - 4096;
        int w = t >> 10; t &= 1023;
        const float* in = w == 0 ? Wq : (w == 1 ? Wk : Wv);
        transpose_tile32(in, WT + (size_t)w * 1024 * 1024, 1024, 1024,
                         t & 31, t >> 5, tid);
    } else if (idx < 9216) {
        int t = idx - 7168;
        transpose_tile32(W1, W1T, 2048, 1024, t & 31, t >> 5, tid);
    } else if (idx < 10240) {
        int t = idx - 9216;
        transpose_tile32(W2, W2T, 1024, 1024, t & 31, t >> 5, tid);
    } else {
        int t = idx - 10240;
        f32x4 zero = {0.f, 0.f, 0.f, 0.f};
        float* p = rsum + ((size_t)t * 256 + tid) * 8;
        *(f32x4*)p = zero;
        *(f32x4*)(p + 4) = zero;
    }
}

// ---------------------------------------------------------------------------
extern "C" void kernel_launch(void* const* d_in, const int* in_sizes, int n_in,
                              void* d_out, int out_size, void* d_ws, size_t ws_size,
                              hipStream_t stream)
{
    const float* x  = (const float*)d_in[0];   // [8192,1024]
    const float* Wq = (const float*)d_in[1];
    const float* Wk = (const float*)d_in[2];
    const float* Wv = (const float*)d_in[3];
    const float* W1 = (const float*)d_in[4];   // [2048,1024]
    const float* b1 = (const float*)d_in[5];
    const float* W2 = (const float*)d_in[6];   // [1024,1024]
    const float* b2 = (const float*)d_in[7];
    float* out = (float*)d_out;                // [8192,1024] fp32

    size_t off = 0;
    auto alloc = [&](size_t bytes) {
        char* r = (char*)d_ws + off;
        off += (bytes + 255) & ~(size_t)255;
        return r;
    };
    const size_t TOK = (size_t)8192 * 1024;    // tokens x dim
    unsigned short* WT   = (unsigned short*)alloc((size_t)3072 * 1024 * 2);
    unsigned short* W1T  = (unsigned short*)alloc((size_t)1024 * 2048 * 2);
    unsigned short* W2T  = (unsigned short*)alloc((size_t)1024 * 1024 * 2);
    unsigned short* xb   = (unsigned short*)alloc(TOK * 2);
    unsigned short* vT   = (unsigned short*)alloc((size_t)1024 * 8192 * 2); // [d][b*2048+s]
    unsigned short* attn = (unsigned short*)alloc(TOK * 2);
    float*          rsum = (float*)         alloc((size_t)4 * 2048 * 4);
    unsigned short* q    = (unsigned short*)alloc(TOK * 2);
    unsigned short* k    = (unsigned short*)alloc(TOK * 2);   // k = q + TOK
    unsigned short* S    = (unsigned short*)alloc((size_t)4 * 2048 * 2048 * 2);
    unsigned short* h1   = S;                  // S dead after PV; MLP1 out aliases it
    // peak ws use: ~131 MB

    // prep: xb, WT, W1T, W2T, rsum=0 in one launch
    prep_kernel<<<10244, 256, 0, stream>>>(x, Wq, Wk, Wv, W1, W2, xb, WT, W1T, W2T, rsum);

    // q,k = xb @ Wq^T / Wk^T on gemm2p: 256 blocks/z x 2 z = 2 exact rounds
    gemm2p<0, 0, 1><<<dim3(8, 32, 2), 512, 0, stream>>>(
        xb, nullptr, 1024, 0, 0, WT, 1024, q, 1024, 1024,
        (long)1024 * 1024, (long)TOK, nullptr);

    // vT = WvT @ xb^T (swapped operands), n-chunk per XCD: 256 blocks
    gemm2p<0, 0, 2><<<dim3(64, 4, 1), 512, 0, stream>>>(
        WT + (size_t)2 * 1024 * 1024, nullptr, 1024, 0, 0, xb, 1024,
        vT, 8192, 1024, 0, 0, nullptr);

    // scores+softmax fused on 64-row m-tiles: P = exp(q@k^T/32 - 16) (causal),
    // rowsums -> rsum. Triangular grid: 272 blocks/z = 1088 total (4.25/CU).
    gemm128<0, 6, 5, false, 64><<<dim3(272, 1, 4), 256, 0, stream>>>(
        q, nullptr, 1024, 0, 0, k, 1024, S, 2048, 1024,
        (long)2048 * 1024, (long)2048 * 1024, (long)2048 * 2048, rsum, 2048, 0.03125f,
        nullptr, 0);
    // attn = (P @ v) / rsum[row]  (64-row tiles, kend = m0+64; z-complement:
    // each CU's 4 resident blocks sum to constant 66 iters)
    gemm128<0, 4, 4, true, 64><<<dim3(8, 32, 4), 256, 0, stream>>>(
        S, nullptr, 2048, 0, 0, vT, 8192, attn, 1024, 2048,
        (long)2048 * 2048, (long)2048, (long)2048 * 1024, rsum, 2048, 0.f, nullptr, 0);

    // MLP1: h1 = relu([attn | x] @ W1 + b1), split-A concat trick: 256 blocks
    gemm2p<2, 2, 1><<<dim3(8, 32, 1), 512, 0, stream>>>(
        attn, xb, 1024, 1024, 1024, W1T, 2048, h1, 1024, 2048,
        0, 0, b1);
    // MLP2: out = h1 @ W2 + b2 (fp32 to d_out): 256 blocks
    gemm2p<0, 3, 1><<<dim3(8, 32, 1), 512, 0, stream>>>(
        h1, nullptr, 1024, 0, 0, W2T, 1024, out, 1024, 1024,
        0, 0, b2);
}

// Round 5
// 302.763 us; speedup vs baseline: 1.0071x; 1.0071x over previous
//
#include <hip/hip_runtime.h>
#include <stdint.h>

typedef __attribute__((ext_vector_type(8))) short short8;
typedef __attribute__((ext_vector_type(4))) float f32x4;

__device__ __forceinline__ unsigned short f32_to_bf16(float f) {
    unsigned int u = __float_as_uint(f);
    u += 0x7FFFu + ((u >> 16) & 1u);   // round-to-nearest-even
    return (unsigned short)(u >> 16);
}

__device__ __forceinline__ short8 load8_f32_as_bf16(const float* __restrict__ ap) {
    f32x4 f0 = *(const f32x4*)ap;
    f32x4 f1 = *(const f32x4*)(ap + 4);
    union { short8 s; unsigned short u[8]; } cv;
#pragma unroll
    for (int t = 0; t < 4; ++t) {
        cv.u[t]     = f32_to_bf16(f0[t]);
        cv.u[t + 4] = f32_to_bf16(f1[t]);
    }
    return cv.s;
}

// async global->LDS DMA, 16B/lane; LDS dest = wave-uniform base + lane*16 (m104/m108)
__device__ __forceinline__ void gld_lds16(const void* g, void* l) {
    __builtin_amdgcn_global_load_lds(
        (const __attribute__((address_space(1))) unsigned int*)(unsigned long long)(uintptr_t)g,
        (__attribute__((address_space(3))) unsigned int*)(unsigned int)(uintptr_t)l,
        16, 0, 0);
}

// ---------------------------------------------------------------------------
// NT GEMM: C[M,N] = A[M,K]*B[N,K]^T, bf16 in, fp32 accum.
// MT x 128 tile (MT = 128 everywhere now), BK=64, 4 waves.
// LDS swizzle chunk' = c ^ (row&7): SQ_LDS_BANK_CONFLICT == 0 (measured R4).
// Measured 928 TF on the QKV dispatch (R0) -- all five GEMMs now use MT=128.
// SWIZ block mapping:
//  0 = identity
//  1 = xcd-m-chunk: XCD owns contiguous m-chunk, m fast / n slow
//  4 = identity + m-complement for z&2: PV balance -- all 512 blocks resident
//      (2/CU), paired (z0,i)+(z2,15-i) per CU -> per-CU K-work constant.
//  5 = triangular causal decode on 128-row m-tiles: cum(i)=i(i+1)/2,
//      x -> (mblk, nblk); m-tile i has n-blocks 0..i (lower triangle only).
//  6 = fused qkv: z<2 -> q,k (m-chunk per XCD); z==2 -> vT build with
//      swapped operands (A=WvT, B=xb) and n-chunk per XCD; C2/ldc2 output.
// AMODE: 0 = A only; 2 = split at ksplit: A then A2 (concat trick for MLP1).
// EPI: 0 bf16 | 2 relu(+bias[col]) bf16 | 3 +bias[col] fp32
//      4 *(1/bias[z*bS+row]) bf16 (PV: divide by softmax rowsum)
//      6 exp(v*scale-16) masked col<=row, bf16 + atomicAdd rowsums into bias
//        (fused softmax; const max-shift 16 exact for ratios, s>16 ~8 sigma)
// KLIMIT: kend = min(K, m0+MT)  (PV: S cols beyond m-tile's diag block are
//         never written; kend covers exactly the n-blocks j<=i scores wrote).
// ---------------------------------------------------------------------------
template<int AMODE, int EPI, int SWIZ, bool KLIMIT, int MT>
__global__ __launch_bounds__(256, 4)
void gemm128(const unsigned short* __restrict__ A, const unsigned short* __restrict__ A2,
             int lda, int lda2, int ksplit,
             const unsigned short* __restrict__ B, int ldb,
             void* __restrict__ C, int ldc, int K,
             long aStride, long bStride, long cStride,
             const float* __restrict__ bias, long biasStride, float scale,
             void* __restrict__ C2, int ldc2)
{
    int z = blockIdx.z;
    int mblk, nblk;
    if (SWIZ == 1) {
        int lin = blockIdx.y * gridDim.x + blockIdx.x;
        int mchunk = gridDim.y >> 3;
        int xcd = lin & 7, idx = lin >> 3;
        mblk = xcd * mchunk + idx % mchunk;   // m fast within XCD's chunk
        nblk = idx / mchunk;                  // n slow
    } else if (SWIZ == 4) {
        mblk = (z & 2) ? ((int)gridDim.y - 1 - (int)blockIdx.y) : blockIdx.y;
        nblk = blockIdx.x;
    } else if (SWIZ == 5) {
        // triangle over 128-row m-tiles: cum(i) = i(i+1)/2, i in [0,16)
        int x = blockIdx.x;
        int a = (int)sqrtf(2.f * (float)x + 1.f);
        if (a > 15) a = 15;
        while (a < 15 && ((a + 1) * (a + 2) / 2) <= x) ++a;
        while (a > 0 && (a * (a + 1) / 2) > x) --a;
        mblk = a;
        nblk = x - a * (a + 1) / 2;
    } else if (SWIZ == 6) {
        int x = blockIdx.x, yy = blockIdx.y;
        if (z < 2) { mblk = x * 8 + (yy & 7); nblk = yy >> 3; }
        else       { nblk = x * 8 + (yy & 7); mblk = yy >> 3; }
    } else {
        mblk = blockIdx.y;
        nblk = blockIdx.x;
    }
    int m0 = mblk * MT;
    int n0 = nblk * 128;

    const unsigned short* Ab;
    const unsigned short* Bb;
    if (SWIZ == 6) {
        if (z < 2) { Ab = A; Bb = B + (size_t)z * bStride; }
        else       { Ab = B + (size_t)2 * bStride; Bb = A; }
    } else {
        Ab = A + (size_t)z * aStride;
        Bb = B + (size_t)z * bStride;
    }

    __shared__ __align__(16) short As[MT * 64];
    __shared__ __align__(16) short Bs[128 * 64];

    int tid  = threadIdx.x;
    int lane = tid & 63, wid = tid >> 6;
    constexpr int MI = MT / 32;              // a-frag / acc-row count per wave
    int wm = (wid & 1) * (MT / 2), wn = (wid >> 1) * 64;
    int fr = lane & 15, fq = lane >> 4;
    // fragment-read byte offsets within a 128B row (lane-constant):
    // global chunk g = kh*4+fq lives in slot g^(row&7); row&7 == fr&7 here
    int sw0 = ((fq    ) ^ (fr & 7)) * 16;
    int sw1 = ((fq ^ 4) ^ (fr & 7)) * 16;

    // DMA staging: thread covers rows rS + 32t, swizzled source chunk
    int rS = tid >> 3;
    int cS = ((tid & 7) ^ (rS & 7)) * 8;   // element offset in k
    char* AsB = (char*)As; char* BsB = (char*)Bs;

    int kend = KLIMIT ? min(K, m0 + MT) : K;

    f32x4 acc[MI][4];
#pragma unroll
    for (int i = 0; i < MI; ++i)
#pragma unroll
    for (int j = 0; j < 4; ++j) acc[i][j] = f32x4{0.f, 0.f, 0.f, 0.f};

    for (int k0 = 0; k0 < kend; k0 += 64) {
        const unsigned short* Asrc = Ab;
        int koff = k0, ldax = lda;
        if (AMODE == 2 && k0 >= ksplit) { Asrc = A2; koff = k0 - ksplit; ldax = lda2; }
        const unsigned short* pa = Asrc + (size_t)(m0 + rS) * ldax + koff + cS;
        const unsigned short* pb = Bb   + (size_t)(n0 + rS) * ldb  + k0   + cS;
#pragma unroll
        for (int t = 0; t < MT / 32; ++t)
            gld_lds16(pa + (size_t)(32 * t) * ldax, AsB + t * 4096 + tid * 16);
#pragma unroll
        for (int t = 0; t < 4; ++t)
            gld_lds16(pb + (size_t)(32 * t) * ldb,  BsB + t * 4096 + tid * 16);
        __syncthreads();

#pragma unroll
        for (int kh = 0; kh < 2; ++kh) {
            int sw = kh ? sw1 : sw0;
            short8 a[MI], b[4];
#pragma unroll
            for (int i = 0; i < MI; ++i)
                a[i] = *(const short8*)(AsB + (wm + i * 16 + fr) * 128 + sw);
#pragma unroll
            for (int j = 0; j < 4; ++j)
                b[j] = *(const short8*)(BsB + (wn + j * 16 + fr) * 128 + sw);
#pragma unroll
            for (int i = 0; i < MI; ++i)
#pragma unroll
            for (int j = 0; j < 4; ++j)
                acc[i][j] = __builtin_amdgcn_mfma_f32_16x16x32_bf16(a[i], b[j], acc[i][j], 0, 0, 0);
        }
        __syncthreads();
    }

    // epilogue: C/D layout col = lane&15, row = (lane>>4)*4 + reg [m89/m91]
    if (EPI == 0) {
        unsigned short* Cz; int ldcz;
        if (SWIZ == 6 && z >= 2) { Cz = (unsigned short*)C2; ldcz = ldc2; }
        else { Cz = (unsigned short*)C + (size_t)z * cStride; ldcz = ldc; }
#pragma unroll
        for (int i = 0; i < MI; ++i)
#pragma unroll
        for (int j = 0; j < 4; ++j)
#pragma unroll
        for (int r = 0; r < 4; ++r) {
            int row = m0 + wm + i * 16 + fq * 4 + r;
            int col = n0 + wn + j * 16 + fr;
            Cz[(size_t)row * ldcz + col] = f32_to_bf16(acc[i][j][r]);
        }
    } else if (EPI == 6) {
        unsigned short* Cz = (unsigned short*)C + (size_t)z * cStride;
        float* rs = const_cast<float*>(bias) + z * biasStride;
#pragma unroll
        for (int i = 0; i < MI; ++i)
#pragma unroll
        for (int r = 0; r < 4; ++r) {
            int row = m0 + wm + i * 16 + fq * 4 + r;
            float s = 0.f;
#pragma unroll
            for (int j = 0; j < 4; ++j) {
                int col = n0 + wn + j * 16 + fr;
                float e = (col <= row) ? __expf(acc[i][j][r] * scale - 16.f) : 0.f;
                s += e;
                Cz[(size_t)row * ldc + col] = f32_to_bf16(e);
            }
            s += __shfl_xor(s, 1);
            s += __shfl_xor(s, 2);
            s += __shfl_xor(s, 4);
            s += __shfl_xor(s, 8);      // reduced over the 16 fr-lanes
            if (fr == 0) atomicAdd(&rs[row], s);
        }
    } else if (EPI == 4) {
        unsigned short* Cz = (unsigned short*)C + (size_t)z * cStride;
#pragma unroll
        for (int i = 0; i < MI; ++i)
#pragma unroll
        for (int r = 0; r < 4; ++r) {
            int row = m0 + wm + i * 16 + fq * 4 + r;
            float inv = 1.f / bias[z * biasStride + row];
#pragma unroll
            for (int j = 0; j < 4; ++j) {
                int col = n0 + wn + j * 16 + fr;
                Cz[(size_t)row * ldc + col] = f32_to_bf16(acc[i][j][r] * inv);
            }
        }
    } else {
#pragma unroll
        for (int i = 0; i < MI; ++i)
#pragma unroll
        for (int j = 0; j < 4; ++j)
#pragma unroll
        for (int r = 0; r < 4; ++r) {
            int row = m0 + wm + i * 16 + fq * 4 + r;
            int col = n0 + wn + j * 16 + fr;
            float v = acc[i][j][r];
            if (EPI == 2) {
                v += bias[col];
                v = v > 0.f ? v : 0.f;
                ((unsigned short*)C + (size_t)z * cStride)[(size_t)row * ldc + col] = f32_to_bf16(v);
            } else {   // 3
                ((float*)C + (size_t)z * cStride)[(size_t)row * ldc + col] = v + bias[col];
            }
        }
    }
}

// ---------------------------------------------------------------------------
// one prep launch: xb = bf16(x); WT = [Wq;Wk;Wv]^T; W1T; W2T; rsum = 0.
// zones: [0,4096) xb | [4096,7168) Wqkv^T | [7168,9216) W1^T |
//        [9216,10240) W2^T | [10240,10244) rsum zero
// ---------------------------------------------------------------------------
__device__ __forceinline__ void transpose_tile32(const float* __restrict__ in,
                                                 unsigned short* __restrict__ out,
                                                 int rows, int cols, int bx, int by, int tid)
{
    __shared__ float t[32][33];
    int tx = tid & 31, ty = tid >> 5;   // 32 x 8
    int r0 = by * 32, c0 = bx * 32;
#pragma unroll
    for (int i = 0; i < 4; ++i)
        t[ty + i * 8][tx] = in[(size_t)(r0 + ty + i * 8) * cols + c0 + tx];
    __syncthreads();
#pragma unroll
    for (int i = 0; i < 4; ++i)
        out[(size_t)(c0 + ty + i * 8) * rows + r0 + tx] = f32_to_bf16(t[tx][ty + i * 8]);
}

__global__ __launch_bounds__(256)
void prep_kernel(const float* __restrict__ x,
                 const float* __restrict__ Wq, const float* __restrict__ Wk,
                 const float* __restrict__ Wv, const float* __restrict__ W1,
                 const float* __restrict__ W2,
                 unsigned short* __restrict__ xb, unsigned short* __restrict__ WT,
                 unsigned short* __restrict__ W1T, unsigned short* __restrict__ W2T,
                 float* __restrict__ rsum)
{
    int idx = blockIdx.x;
    int tid = threadIdx.x;
    if (idx < 4096) {
        size_t i = ((size_t)idx * 256 + tid) * 8;
        *(short8*)(xb + i) = load8_f32_as_bf16(x + i);
    } else if (idx < 7168) {
        int t = idx - 4096;
        int w = t >> 10; t &= 1023;
        const float* in = w == 0 ? Wq : (w == 1 ? Wk : Wv);
        transpose_tile32(in, WT + (size_t)w * 1024 * 1024, 1024, 1024,
                         t & 31, t >> 5, tid);
    } else if (idx < 9216) {
        int t = idx - 7168;
        transpose_tile32(W1, W1T, 2048, 1024, t & 31, t >> 5, tid);
    } else if (idx < 10240) {
        int t = idx - 9216;
        transpose_tile32(W2, W2T, 1024, 1024, t & 31, t >> 5, tid);
    } else {
        int t = idx - 10240;
        f32x4 zero = {0.f, 0.f, 0.f, 0.f};
        float* p = rsum + ((size_t)t * 256 + tid) * 8;
        *(f32x4*)p = zero;
        *(f32x4*)(p + 4) = zero;
    }
}

// ---------------------------------------------------------------------------
extern "C" void kernel_launch(void* const* d_in, const int* in_sizes, int n_in,
                              void* d_out, int out_size, void* d_ws, size_t ws_size,
                              hipStream_t stream)
{
    const float* x  = (const float*)d_in[0];   // [8192,1024]
    const float* Wq = (const float*)d_in[1];
    const float* Wk = (const float*)d_in[2];
    const float* Wv = (const float*)d_in[3];
    const float* W1 = (const float*)d_in[4];   // [2048,1024]
    const float* b1 = (const float*)d_in[5];
    const float* W2 = (const float*)d_in[6];   // [1024,1024]
    const float* b2 = (const float*)d_in[7];
    float* out = (float*)d_out;                // [8192,1024] fp32

    size_t off = 0;
    auto alloc = [&](size_t bytes) {
        char* r = (char*)d_ws + off;
        off += (bytes + 255) & ~(size_t)255;
        return r;
    };
    const size_t TOK = (size_t)8192 * 1024;    // tokens x dim
    unsigned short* WT   = (unsigned short*)alloc((size_t)3072 * 1024 * 2);
    unsigned short* W1T  = (unsigned short*)alloc((size_t)1024 * 2048 * 2);
    unsigned short* W2T  = (unsigned short*)alloc((size_t)1024 * 1024 * 2);
    unsigned short* xb   = (unsigned short*)alloc(TOK * 2);
    unsigned short* vT   = (unsigned short*)alloc((size_t)1024 * 8192 * 2); // [d][b*2048+s]
    unsigned short* attn = (unsigned short*)alloc(TOK * 2);
    float*          rsum = (float*)         alloc((size_t)4 * 2048 * 4);
    unsigned short* q    = (unsigned short*)alloc(TOK * 2);
    unsigned short* k    = (unsigned short*)alloc(TOK * 2);
    unsigned short* S    = (unsigned short*)alloc((size_t)4 * 2048 * 2048 * 2);
    unsigned short* h1   = S;                  // S dead after PV; MLP1 out aliases it
    // peak ws use: ~131 MB

    // prep: xb, WT, W1T, W2T, rsum=0 in one launch
    prep_kernel<<<10244, 256, 0, stream>>>(x, Wq, Wk, Wv, W1, W2, xb, WT, W1T, W2T, rsum);

    // fused q,k,vT (z<2: q,k = xb @ Wqk^T m-chunked; z==2: vT = WvT @ xb^T
    // n-chunked). 1536 blocks. Measured 55.5 us / 928 TF (R0).
    gemm128<0, 0, 6, false, 128><<<dim3(8, 64, 3), 256, 0, stream>>>(
        xb, nullptr, 1024, 0, 0, WT, 1024, q, 1024, 1024,
        0, (long)1024 * 1024, (long)TOK, nullptr, 0, 0.f, vT, 8192);

    // scores+softmax fused on 128-row m-tiles: P = exp(q@k^T/32 - 16)
    // (causal), rowsums -> rsum. Triangular grid: 136 blocks/z = 544 total,
    // uniform K=1024, all resident at 4 blk/CU.
    gemm128<0, 6, 5, false, 128><<<dim3(136, 1, 4), 256, 0, stream>>>(
        q, nullptr, 1024, 0, 0, k, 1024, S, 2048, 1024,
        (long)2048 * 1024, (long)2048 * 1024, (long)2048 * 2048, rsum, 2048, 0.03125f,
        nullptr, 0);
    // attn = (P @ v) / rsum[row]  (128-row tiles, kend = m0+128; z-complement:
    // 512 blocks all resident 2/CU, per-CU K-work constant)
    gemm128<0, 4, 4, true, 128><<<dim3(8, 16, 4), 256, 0, stream>>>(
        S, nullptr, 2048, 0, 0, vT, 8192, attn, 1024, 2048,
        (long)2048 * 2048, (long)2048, (long)2048 * 1024, rsum, 2048, 0.f, nullptr, 0);

    // MLP1: h1 = relu([attn | x] @ W1 + b1), split-A concat trick.
    // Output is [8192 x 1024] -> 64 m-tiles x 8 n-blocks = 512 blocks
    // (2 exact rounds), uniform K=2048.
    gemm128<2, 2, 1, false, 128><<<dim3(8, 64, 1), 256, 0, stream>>>(
        attn, xb, 1024, 1024, 1024, W1T, 2048, h1, 1024, 2048, 0, 0, 0, b1, 0, 0.f,
        nullptr, 0);
    // MLP2: out = h1 @ W2 + b2 (fp32 to d_out), 512 blocks = 2 exact rounds
    gemm128<0, 3, 1, false, 128><<<dim3(8, 64, 1), 256, 0, stream>>>(
        h1, nullptr, 1024, 0, 0, W2T, 1024, out, 1024, 1024, 0, 0, 0, b2, 0, 0.f,
        nullptr, 0);
}

// Round 6
// 289.905 us; speedup vs baseline: 1.0517x; 1.0444x over previous
//
#include <hip/hip_runtime.h>
#include <stdint.h>

typedef __attribute__((ext_vector_type(8))) short short8;
typedef __attribute__((ext_vector_type(4))) short short4v;
typedef __attribute__((ext_vector_type(4))) float f32x4;

__device__ __forceinline__ unsigned short f32_to_bf16(float f) {
    unsigned int u = __float_as_uint(f);
    u += 0x7FFFu + ((u >> 16) & 1u);   // round-to-nearest-even
    return (unsigned short)(u >> 16);
}

__device__ __forceinline__ short8 load8_f32_as_bf16(const float* __restrict__ ap) {
    f32x4 f0 = *(const f32x4*)ap;
    f32x4 f1 = *(const f32x4*)(ap + 4);
    union { short8 s; unsigned short u[8]; } cv;
#pragma unroll
    for (int t = 0; t < 4; ++t) {
        cv.u[t]     = f32_to_bf16(f0[t]);
        cv.u[t + 4] = f32_to_bf16(f1[t]);
    }
    return cv.s;
}

// async global->LDS DMA, 16B/lane; LDS dest = wave-uniform base + lane*16 (m104/m108)
__device__ __forceinline__ void gld_lds16(const void* g, void* l) {
    __builtin_amdgcn_global_load_lds(
        (const __attribute__((address_space(1))) unsigned int*)(unsigned long long)(uintptr_t)g,
        (__attribute__((address_space(3))) unsigned int*)(unsigned int)(uintptr_t)l,
        16, 0, 0);
}

// ---------------------------------------------------------------------------
// NT GEMM: C[M,N] = A[M,K]*B[N,K]^T, bf16 in, fp32 accum.
// MT x 128 tile, BK=64, 4 waves. LDS swizzle chunk' = c ^ (row&7):
// SQ_LDS_BANK_CONFLICT == 0 (measured). QKV dispatch measured 928 TF.
// SWIZ block mapping:
//  1 = xcd-m-chunk: XCD owns contiguous m-chunk, m fast / n slow
//  5 = triangular causal decode on 128-row m-tiles WITH xcd pre-permute:
//      x' = (x%8)*(nx/8) + x/8 (bijective, gridDim.x%8==0) -> each XCD owns
//      a contiguous run of tri indices -> q/k tile reuse stays in its L2.
//      cum(i)=i(i+1)/2; m-tile i has n-blocks 0..i.
//  6 = fused qkv: z<2 -> q,k (m-chunk per XCD); z==2 -> vT build with
//      swapped operands (A=WvT, B=xb) and n-chunk per XCD; C2/ldc2 output.
//  7 = PV: decode (z,m,n) from global linear id (grid MUST be (8,16,4)):
//      xcd = glin%8 (round-robin heuristic), z = xcd>>1 -> each XCD pair
//      owns one batch's 4MB vT slice (fits its L2). Balanced m-set per XCD:
//      h=xcd&1, slot s=glin>>3: jm=s&7, n=s>>3,
//      m = (jm&1) ? (15-h-(jm>>1)*2) : ((jm>>1)*2+h)  -> per-XCD sum of
//      kend units = 68 = const (work-balanced). Bijective over 512 blocks.
// AMODE: 0 = A only; 2 = split at ksplit: A then A2 (concat trick for MLP1).
// EPI: 0 bf16 | 2 relu(+bias[col]) bf16 | 3 +bias[col] fp32
//      4 *(1/bias[z*bS+row]) bf16 (PV: divide by softmax rowsum)
//      6 exp(v*scale-16) masked col<=row, bf16 + atomicAdd rowsums into bias
// KLIMIT: kend = min(K, m0+MT)  (PV: covers exactly the n-blocks scores wrote)
// ---------------------------------------------------------------------------
template<int AMODE, int EPI, int SWIZ, bool KLIMIT, int MT>
__global__ __launch_bounds__(256, 4)
void gemm128(const unsigned short* __restrict__ A, const unsigned short* __restrict__ A2,
             int lda, int lda2, int ksplit,
             const unsigned short* __restrict__ B, int ldb,
             void* __restrict__ C, int ldc, int K,
             long aStride, long bStride, long cStride,
             const float* __restrict__ bias, long biasStride, float scale,
             void* __restrict__ C2, int ldc2)
{
    int z = blockIdx.z;
    int mblk, nblk;
    if (SWIZ == 1) {
        int lin = blockIdx.y * gridDim.x + blockIdx.x;
        int mchunk = gridDim.y >> 3;
        int xcd = lin & 7, idx = lin >> 3;
        mblk = xcd * mchunk + idx % mchunk;   // m fast within XCD's chunk
        nblk = idx / mchunk;                  // n slow
    } else if (SWIZ == 5) {
        // xcd pre-permute then triangle decode (i in [0,16))
        int x = blockIdx.x;
        int per = (int)gridDim.x >> 3;        // 136/8 = 17
        x = (x & 7) * per + (x >> 3);
        int a = (int)sqrtf(2.f * (float)x + 1.f);
        if (a > 15) a = 15;
        while (a < 15 && ((a + 1) * (a + 2) / 2) <= x) ++a;
        while (a > 0 && (a * (a + 1) / 2) > x) --a;
        mblk = a;
        nblk = x - a * (a + 1) / 2;
    } else if (SWIZ == 6) {
        int x = blockIdx.x, yy = blockIdx.y;
        if (z < 2) { mblk = x * 8 + (yy & 7); nblk = yy >> 3; }
        else       { nblk = x * 8 + (yy & 7); mblk = yy >> 3; }
    } else if (SWIZ == 7) {
        int glin = (int)blockIdx.z * 128 + (int)blockIdx.y * 8 + (int)blockIdx.x;
        int xcd = glin & 7;
        int s   = glin >> 3;                  // [0,64) per xcd
        z = xcd >> 1;                         // batch owned by this xcd pair
        int h  = xcd & 1;
        int jm = s & 7;
        nblk   = s >> 3;                      // [0,8)
        mblk   = (jm & 1) ? (15 - h - (jm >> 1) * 2) : ((jm >> 1) * 2 + h);
    } else {
        mblk = blockIdx.y;
        nblk = blockIdx.x;
    }
    int m0 = mblk * MT;
    int n0 = nblk * 128;

    const unsigned short* Ab;
    const unsigned short* Bb;
    if (SWIZ == 6) {
        if (z < 2) { Ab = A; Bb = B + (size_t)z * bStride; }
        else       { Ab = B + (size_t)2 * bStride; Bb = A; }
    } else {
        Ab = A + (size_t)z * aStride;
        Bb = B + (size_t)z * bStride;
    }

    __shared__ __align__(16) short As[MT * 64];
    __shared__ __align__(16) short Bs[128 * 64];

    int tid  = threadIdx.x;
    int lane = tid & 63, wid = tid >> 6;
    constexpr int MI = MT / 32;              // a-frag / acc-row count per wave
    int wm = (wid & 1) * (MT / 2), wn = (wid >> 1) * 64;
    int fr = lane & 15, fq = lane >> 4;
    // fragment-read byte offsets within a 128B row (lane-constant):
    // global chunk g = kh*4+fq lives in slot g^(row&7); row&7 == fr&7 here
    int sw0 = ((fq    ) ^ (fr & 7)) * 16;
    int sw1 = ((fq ^ 4) ^ (fr & 7)) * 16;

    // DMA staging: thread covers rows rS + 32t, swizzled source chunk
    int rS = tid >> 3;
    int cS = ((tid & 7) ^ (rS & 7)) * 8;   // element offset in k
    char* AsB = (char*)As; char* BsB = (char*)Bs;

    int kend = KLIMIT ? min(K, m0 + MT) : K;

    f32x4 acc[MI][4];
#pragma unroll
    for (int i = 0; i < MI; ++i)
#pragma unroll
    for (int j = 0; j < 4; ++j) acc[i][j] = f32x4{0.f, 0.f, 0.f, 0.f};

    for (int k0 = 0; k0 < kend; k0 += 64) {
        const unsigned short* Asrc = Ab;
        int koff = k0, ldax = lda;
        if (AMODE == 2 && k0 >= ksplit) { Asrc = A2; koff = k0 - ksplit; ldax = lda2; }
        const unsigned short* pa = Asrc + (size_t)(m0 + rS) * ldax + koff + cS;
        const unsigned short* pb = Bb   + (size_t)(n0 + rS) * ldb  + k0   + cS;
#pragma unroll
        for (int t = 0; t < MT / 32; ++t)
            gld_lds16(pa + (size_t)(32 * t) * ldax, AsB + t * 4096 + tid * 16);
#pragma unroll
        for (int t = 0; t < 4; ++t)
            gld_lds16(pb + (size_t)(32 * t) * ldb,  BsB + t * 4096 + tid * 16);
        __syncthreads();

#pragma unroll
        for (int kh = 0; kh < 2; ++kh) {
            int sw = kh ? sw1 : sw0;
            short8 a[MI], b[4];
#pragma unroll
            for (int i = 0; i < MI; ++i)
                a[i] = *(const short8*)(AsB + (wm + i * 16 + fr) * 128 + sw);
#pragma unroll
            for (int j = 0; j < 4; ++j)
                b[j] = *(const short8*)(BsB + (wn + j * 16 + fr) * 128 + sw);
#pragma unroll
            for (int i = 0; i < MI; ++i)
#pragma unroll
            for (int j = 0; j < 4; ++j)
                acc[i][j] = __builtin_amdgcn_mfma_f32_16x16x32_bf16(a[i], b[j], acc[i][j], 0, 0, 0);
        }
        __syncthreads();
    }

    // epilogue: C/D layout col = lane&15, row = (lane>>4)*4 + reg [m89/m91]
    if (EPI == 0) {
        unsigned short* Cz; int ldcz;
        if (SWIZ == 6 && z >= 2) { Cz = (unsigned short*)C2; ldcz = ldc2; }
        else { Cz = (unsigned short*)C + (size_t)z * cStride; ldcz = ldc; }
#pragma unroll
        for (int i = 0; i < MI; ++i)
#pragma unroll
        for (int j = 0; j < 4; ++j)
#pragma unroll
        for (int r = 0; r < 4; ++r) {
            int row = m0 + wm + i * 16 + fq * 4 + r;
            int col = n0 + wn + j * 16 + fr;
            Cz[(size_t)row * ldcz + col] = f32_to_bf16(acc[i][j][r]);
        }
    } else if (EPI == 6) {
        unsigned short* Cz = (unsigned short*)C + (size_t)z * cStride;
        float* rs = const_cast<float*>(bias) + z * biasStride;
#pragma unroll
        for (int i = 0; i < MI; ++i)
#pragma unroll
        for (int r = 0; r < 4; ++r) {
            int row = m0 + wm + i * 16 + fq * 4 + r;
            float s = 0.f;
#pragma unroll
            for (int j = 0; j < 4; ++j) {
                int col = n0 + wn + j * 16 + fr;
                float e = (col <= row) ? __expf(acc[i][j][r] * scale - 16.f) : 0.f;
                s += e;
                Cz[(size_t)row * ldc + col] = f32_to_bf16(e);
            }
            s += __shfl_xor(s, 1);
            s += __shfl_xor(s, 2);
            s += __shfl_xor(s, 4);
            s += __shfl_xor(s, 8);      // reduced over the 16 fr-lanes
            if (fr == 0) atomicAdd(&rs[row], s);
        }
    } else if (EPI == 4) {
        unsigned short* Cz = (unsigned short*)C + (size_t)z * cStride;
#pragma unroll
        for (int i = 0; i < MI; ++i)
#pragma unroll
        for (int r = 0; r < 4; ++r) {
            int row = m0 + wm + i * 16 + fq * 4 + r;
            float inv = 1.f / bias[z * biasStride + row];
#pragma unroll
            for (int j = 0; j < 4; ++j) {
                int col = n0 + wn + j * 16 + fr;
                Cz[(size_t)row * ldc + col] = f32_to_bf16(acc[i][j][r] * inv);
            }
        }
    } else {
#pragma unroll
        for (int i = 0; i < MI; ++i)
#pragma unroll
        for (int j = 0; j < 4; ++j)
#pragma unroll
        for (int r = 0; r < 4; ++r) {
            int row = m0 + wm + i * 16 + fq * 4 + r;
            int col = n0 + wn + j * 16 + fr;
            float v = acc[i][j][r];
            if (EPI == 2) {
                v += bias[col];
                v = v > 0.f ? v : 0.f;
                ((unsigned short*)C + (size_t)z * cStride)[(size_t)row * ldc + col] = f32_to_bf16(v);
            } else {   // 3
                ((float*)C + (size_t)z * cStride)[(size_t)row * ldc + col] = v + bias[col];
            }
        }
    }
}

// ---------------------------------------------------------------------------
// prep (rewritten R6): prep was bounded >=36 us (R5 top-5 analysis) for 84 MB
// of traffic. Now: 64x64 transpose tiles with f32x4 loads / short4 stores
// (16 elems/thread) and 32-elems/thread xb convert -> 2564 blocks total.
// zones: [0,1024) xb | [1024,1792) Wqkv^T | [1792,2304) W1^T |
//        [2304,2560) W2^T | [2560,2564) rsum zero
// ---------------------------------------------------------------------------
__device__ __forceinline__ void transpose_tile64(const float* __restrict__ in,
                                                 unsigned short* __restrict__ out,
                                                 int rows, int cols, int bx, int by, int tid)
{
    __shared__ float t[64][65];
    int tx = tid & 15, ty = tid >> 4;   // 16 x 16
    int r0 = by * 64, c0 = bx * 64;
#pragma unroll
    for (int i = 0; i < 4; ++i) {
        f32x4 v = *(const f32x4*)(in + (size_t)(r0 + ty + i * 16) * cols + c0 + tx * 4);
#pragma unroll
        for (int j = 0; j < 4; ++j) t[ty + i * 16][tx * 4 + j] = v[j];
    }
    __syncthreads();
#pragma unroll
    for (int i = 0; i < 4; ++i) {
        union { short4v s; unsigned short u[4]; } o;
#pragma unroll
        for (int j = 0; j < 4; ++j) o.u[j] = f32_to_bf16(t[tx * 4 + j][ty + i * 16]);
        *(short4v*)(out + (size_t)(c0 + ty + i * 16) * rows + r0 + tx * 4) = o.s;
    }
}

__global__ __launch_bounds__(256)
void prep_kernel(const float* __restrict__ x,
                 const float* __restrict__ Wq, const float* __restrict__ Wk,
                 const float* __restrict__ Wv, const float* __restrict__ W1,
                 const float* __restrict__ W2,
                 unsigned short* __restrict__ xb, unsigned short* __restrict__ WT,
                 unsigned short* __restrict__ W1T, unsigned short* __restrict__ W2T,
                 float* __restrict__ rsum)
{
    int idx = blockIdx.x;
    int tid = threadIdx.x;
    if (idx < 1024) {
#pragma unroll
        for (int it = 0; it < 4; ++it) {
            size_t i = ((size_t)idx * 4 + it) * 2048 + (size_t)tid * 8;
            *(short8*)(xb + i) = load8_f32_as_bf16(x + i);
        }
    } else if (idx < 1792) {
        int t = idx - 1024;
        int w = t >> 8; t &= 255;
        const float* in = w == 0 ? Wq : (w == 1 ? Wk : Wv);
        transpose_tile64(in, WT + (size_t)w * 1024 * 1024, 1024, 1024,
                         t & 15, t >> 4, tid);
    } else if (idx < 2304) {
        int t = idx - 1792;                  // 512 tiles: 32 row-tiles x 16
        transpose_tile64(W1, W1T, 2048, 1024, t & 15, t >> 4, tid);
    } else if (idx < 2560) {
        int t = idx - 2304;                  // 256 tiles
        transpose_tile64(W2, W2T, 1024, 1024, t & 15, t >> 4, tid);
    } else {
        int t = idx - 2560;
        f32x4 zero = {0.f, 0.f, 0.f, 0.f};
        float* p = rsum + ((size_t)t * 256 + tid) * 8;
        *(f32x4*)p = zero;
        *(f32x4*)(p + 4) = zero;
    }
}

// ---------------------------------------------------------------------------
extern "C" void kernel_launch(void* const* d_in, const int* in_sizes, int n_in,
                              void* d_out, int out_size, void* d_ws, size_t ws_size,
                              hipStream_t stream)
{
    const float* x  = (const float*)d_in[0];   // [8192,1024]
    const float* Wq = (const float*)d_in[1];
    const float* Wk = (const float*)d_in[2];
    const float* Wv = (const float*)d_in[3];
    const float* W1 = (const float*)d_in[4];   // [2048,1024]
    const float* b1 = (const float*)d_in[5];
    const float* W2 = (const float*)d_in[6];   // [1024,1024]
    const float* b2 = (const float*)d_in[7];
    float* out = (float*)d_out;                // [8192,1024] fp32

    size_t off = 0;
    auto alloc = [&](size_t bytes) {
        char* r = (char*)d_ws + off;
        off += (bytes + 255) & ~(size_t)255;
        return r;
    };
    const size_t TOK = (size_t)8192 * 1024;    // tokens x dim
    unsigned short* WT   = (unsigned short*)alloc((size_t)3072 * 1024 * 2);
    unsigned short* W1T  = (unsigned short*)alloc((size_t)1024 * 2048 * 2);
    unsigned short* W2T  = (unsigned short*)alloc((size_t)1024 * 1024 * 2);
    unsigned short* xb   = (unsigned short*)alloc(TOK * 2);
    unsigned short* vT   = (unsigned short*)alloc((size_t)1024 * 8192 * 2); // [d][b*2048+s]
    unsigned short* attn = (unsigned short*)alloc(TOK * 2);
    float*          rsum = (float*)         alloc((size_t)4 * 2048 * 4);
    unsigned short* q    = (unsigned short*)alloc(TOK * 2);
    unsigned short* k    = (unsigned short*)alloc(TOK * 2);
    unsigned short* S    = (unsigned short*)alloc((size_t)4 * 2048 * 2048 * 2);
    unsigned short* h1   = S;                  // S dead after PV; MLP1 out aliases it
    // peak ws use: ~131 MB

    // prep: xb, WT, W1T, W2T, rsum=0 in one launch (2564 blocks, vectorized)
    prep_kernel<<<2564, 256, 0, stream>>>(x, Wq, Wk, Wv, W1, W2, xb, WT, W1T, W2T, rsum);

    // fused q,k,vT (z<2: q,k = xb @ Wqk^T m-chunked; z==2: vT = WvT @ xb^T
    // n-chunked). 1536 blocks. Measured 53.3 us / 966 TF (R5).
    gemm128<0, 0, 6, false, 128><<<dim3(8, 64, 3), 256, 0, stream>>>(
        xb, nullptr, 1024, 0, 0, WT, 1024, q, 1024, 1024,
        0, (long)1024 * 1024, (long)TOK, nullptr, 0, 0.f, vT, 8192);

    // scores+softmax fused on 128-row m-tiles: P = exp(q@k^T/32 - 16)
    // (causal), rowsums -> rsum. Triangular grid 136/z, xcd pre-permute
    // (each XCD owns 17 contiguous tri indices).
    gemm128<0, 6, 5, false, 128><<<dim3(136, 1, 4), 256, 0, stream>>>(
        q, nullptr, 1024, 0, 0, k, 1024, S, 2048, 1024,
        (long)2048 * 1024, (long)2048 * 1024, (long)2048 * 2048, rsum, 2048, 0.03125f,
        nullptr, 0);
    // attn = (P @ v) / rsum[row]  (128-row tiles, kend = m0+128; SWIZ=7:
    // z per xcd-pair (vT slice fits its L2) + balanced m-sets, grid (8,16,4))
    gemm128<0, 4, 7, true, 128><<<dim3(8, 16, 4), 256, 0, stream>>>(
        S, nullptr, 2048, 0, 0, vT, 8192, attn, 1024, 2048,
        (long)2048 * 2048, (long)2048, (long)2048 * 1024, rsum, 2048, 0.f, nullptr, 0);

    // MLP1: h1 = relu([attn | x] @ W1 + b1), split-A concat trick.
    // [8192 x 1024] out -> 64 m-tiles x 8 n-blocks = 512 blocks, K=2048.
    gemm128<2, 2, 1, false, 128><<<dim3(8, 64, 1), 256, 0, stream>>>(
        attn, xb, 1024, 1024, 1024, W1T, 2048, h1, 1024, 2048, 0, 0, 0, b1, 0, 0.f,
        nullptr, 0);
    // MLP2: out = h1 @ W2 + b2 (fp32 to d_out), 512 blocks
    gemm128<0, 3, 1, false, 128><<<dim3(8, 64, 1), 256, 0, stream>>>(
        h1, nullptr, 1024, 0, 0, W2T, 1024, out, 1024, 1024, 0, 0, 0, b2, 0, 0.f,
        nullptr, 0);
}

// Round 7
// 287.475 us; speedup vs baseline: 1.0606x; 1.0085x over previous
//
#include <hip/hip_runtime.h>
#include <stdint.h>

typedef __attribute__((ext_vector_type(8))) short short8;
typedef __attribute__((ext_vector_type(4))) short short4v;
typedef __attribute__((ext_vector_type(4))) float f32x4;

__device__ __forceinline__ unsigned short f32_to_bf16(float f) {
    unsigned int u = __float_as_uint(f);
    u += 0x7FFFu + ((u >> 16) & 1u);   // round-to-nearest-even
    return (unsigned short)(u >> 16);
}

__device__ __forceinline__ short8 load8_f32_as_bf16(const float* __restrict__ ap) {
    f32x4 f0 = *(const f32x4*)ap;
    f32x4 f1 = *(const f32x4*)(ap + 4);
    union { short8 s; unsigned short u[8]; } cv;
#pragma unroll
    for (int t = 0; t < 4; ++t) {
        cv.u[t]     = f32_to_bf16(f0[t]);
        cv.u[t + 4] = f32_to_bf16(f1[t]);
    }
    return cv.s;
}

// async global->LDS DMA, 16B/lane; LDS dest = wave-uniform base + lane*16 (m104/m108)
__device__ __forceinline__ void gld_lds16(const void* g, void* l) {
    __builtin_amdgcn_global_load_lds(
        (const __attribute__((address_space(1))) unsigned int*)(unsigned long long)(uintptr_t)g,
        (__attribute__((address_space(3))) unsigned int*)(unsigned int)(uintptr_t)l,
        16, 0, 0);
}

// ---------------------------------------------------------------------------
// gemm128: single-buffered NT GEMM (m97 structure), kept ONLY for the fused
// QKV launch (1536 blocks = 6/CU -> cross-block overlap hides the barrier
// drain; measured 966 TF). Low-residency launches use gemmdb below.
// SWIZ=6: z<2 -> q,k (m-chunk per XCD); z==2 -> vT swapped operands
// (n-chunk per XCD), C2/ldc2 output.
// ---------------------------------------------------------------------------
template<int AMODE, int EPI, int SWIZ, bool KLIMIT, int MT>
__global__ __launch_bounds__(256, 4)
void gemm128(const unsigned short* __restrict__ A, const unsigned short* __restrict__ A2,
             int lda, int lda2, int ksplit,
             const unsigned short* __restrict__ B, int ldb,
             void* __restrict__ C, int ldc, int K,
             long aStride, long bStride, long cStride,
             const float* __restrict__ bias, long biasStride, float scale,
             void* __restrict__ C2, int ldc2)
{
    int z = blockIdx.z;
    int mblk, nblk;
    if (SWIZ == 6) {
        int x = blockIdx.x, yy = blockIdx.y;
        if (z < 2) { mblk = x * 8 + (yy & 7); nblk = yy >> 3; }
        else       { nblk = x * 8 + (yy & 7); mblk = yy >> 3; }
    } else {
        mblk = blockIdx.y;
        nblk = blockIdx.x;
    }
    int m0 = mblk * MT;
    int n0 = nblk * 128;

    const unsigned short* Ab;
    const unsigned short* Bb;
    if (SWIZ == 6) {
        if (z < 2) { Ab = A; Bb = B + (size_t)z * bStride; }
        else       { Ab = B + (size_t)2 * bStride; Bb = A; }
    } else {
        Ab = A + (size_t)z * aStride;
        Bb = B + (size_t)z * bStride;
    }

    __shared__ __align__(16) short As[MT * 64];
    __shared__ __align__(16) short Bs[128 * 64];

    int tid  = threadIdx.x;
    int lane = tid & 63, wid = tid >> 6;
    constexpr int MI = MT / 32;              // a-frag / acc-row count per wave
    int wm = (wid & 1) * (MT / 2), wn = (wid >> 1) * 64;
    int fr = lane & 15, fq = lane >> 4;
    // fragment-read byte offsets within a 128B row (lane-constant):
    // global chunk g = kh*4+fq lives in slot g^(row&7); row&7 == fr&7 here
    int sw0 = ((fq    ) ^ (fr & 7)) * 16;
    int sw1 = ((fq ^ 4) ^ (fr & 7)) * 16;

    // DMA staging: thread covers rows rS + 32t, swizzled source chunk
    int rS = tid >> 3;
    int cS = ((tid & 7) ^ (rS & 7)) * 8;   // element offset in k
    char* AsB = (char*)As; char* BsB = (char*)Bs;

    int kend = KLIMIT ? min(K, m0 + MT) : K;

    f32x4 acc[MI][4];
#pragma unroll
    for (int i = 0; i < MI; ++i)
#pragma unroll
    for (int j = 0; j < 4; ++j) acc[i][j] = f32x4{0.f, 0.f, 0.f, 0.f};

    for (int k0 = 0; k0 < kend; k0 += 64) {
        const unsigned short* Asrc = Ab;
        int koff = k0, ldax = lda;
        if (AMODE == 2 && k0 >= ksplit) { Asrc = A2; koff = k0 - ksplit; ldax = lda2; }
        const unsigned short* pa = Asrc + (size_t)(m0 + rS) * ldax + koff + cS;
        const unsigned short* pb = Bb   + (size_t)(n0 + rS) * ldb  + k0   + cS;
#pragma unroll
        for (int t = 0; t < MT / 32; ++t)
            gld_lds16(pa + (size_t)(32 * t) * ldax, AsB + t * 4096 + tid * 16);
#pragma unroll
        for (int t = 0; t < 4; ++t)
            gld_lds16(pb + (size_t)(32 * t) * ldb,  BsB + t * 4096 + tid * 16);
        __syncthreads();

#pragma unroll
        for (int kh = 0; kh < 2; ++kh) {
            int sw = kh ? sw1 : sw0;
            short8 a[MI], b[4];
#pragma unroll
            for (int i = 0; i < MI; ++i)
                a[i] = *(const short8*)(AsB + (wm + i * 16 + fr) * 128 + sw);
#pragma unroll
            for (int j = 0; j < 4; ++j)
                b[j] = *(const short8*)(BsB + (wn + j * 16 + fr) * 128 + sw);
#pragma unroll
            for (int i = 0; i < MI; ++i)
#pragma unroll
            for (int j = 0; j < 4; ++j)
                acc[i][j] = __builtin_amdgcn_mfma_f32_16x16x32_bf16(a[i], b[j], acc[i][j], 0, 0, 0);
        }
        __syncthreads();
    }

    // epilogue: C/D layout col = lane&15, row = (lane>>4)*4 + reg [m89/m91]
    if (EPI == 0) {
        unsigned short* Cz; int ldcz;
        if (SWIZ == 6 && z >= 2) { Cz = (unsigned short*)C2; ldcz = ldc2; }
        else { Cz = (unsigned short*)C + (size_t)z * cStride; ldcz = ldc; }
#pragma unroll
        for (int i = 0; i < MI; ++i)
#pragma unroll
        for (int j = 0; j < 4; ++j)
#pragma unroll
        for (int r = 0; r < 4; ++r) {
            int row = m0 + wm + i * 16 + fq * 4 + r;
            int col = n0 + wn + j * 16 + fr;
            Cz[(size_t)row * ldcz + col] = f32_to_bf16(acc[i][j][r]);
        }
    }
}

// ---------------------------------------------------------------------------
// gemmdb: DOUBLE-BUFFERED NT GEMM for low-residency launches (512-544 blocks
// = 2 blocks/CU, where the single-buffer structure exposes ~700-900 cyc of
// load latency per K-tile at the vmcnt(0) barrier drain -- R6 elimination
// ledger: these launches run ~600 TF vs QKV's 966 at 6/CU).
// T3 "minimum 2-phase": per iter {STAGE(t+1 -> buf^1); s_waitcnt vmcnt(8)
// [own tile-t loads landed; t+1's 8 stay in flight]; s_barrier [collective];
// ds_read+MFMA on buf[t]; s_barrier [WAR: next iter stages into this buf]}.
// Gate never drains to 0 until the final tile; loads get one full K-tile of
// compute (~1800 cyc) to cover latency. Barrier/sched_barrier/memory-clobber
// discipline identical to R3's gemm2p (correctness-proven).
// MT=128, BK=64, 4 waves, LDS 64 KB (2 buf x [A 16K | B 16K]).
// LDS swizzle chunk' = c ^ (row&7) (zero bank conflicts, measured).
// SWIZ: 1 = xcd-m-chunk (gridDim.y%8==0)
//       5 = triangular causal (136/z) with xcd pre-permute x'=(x%8)*17+x/8
//       7 = PV decode from glin (grid MUST be (8,16,4)): xcd=glin%8,
//           z=xcd>>1 (vT slice per xcd-pair L2), balanced m-sets.
// EPI: 2 relu(+bias[col]) bf16 | 3 +bias[col] fp32 | 4 /rsum bf16 | 6 exp+
//      rowsum-atomics bf16. AMODE 2: A->A2 at ksplit (MLP1 concat).
// KLIMIT: kend = min(K, m0+128).
// ---------------------------------------------------------------------------
template<int AMODE, int EPI, int SWIZ, bool KLIMIT>
__global__ __launch_bounds__(256, 2)
void gemmdb(const unsigned short* __restrict__ A, const unsigned short* __restrict__ A2,
            int lda, int lda2, int ksplit,
            const unsigned short* __restrict__ B, int ldb,
            void* __restrict__ C, int ldc, int K,
            long aStride, long bStride, long cStride,
            const float* __restrict__ bias, long biasStride, float scale)
{
    int z = blockIdx.z;
    int mblk, nblk;
    if (SWIZ == 1) {
        int lin = blockIdx.y * gridDim.x + blockIdx.x;
        int mchunk = gridDim.y >> 3;
        int xcd = lin & 7, idx = lin >> 3;
        mblk = xcd * mchunk + idx % mchunk;   // m fast within XCD's chunk
        nblk = idx / mchunk;                  // n slow
    } else if (SWIZ == 5) {
        // xcd pre-permute then triangle decode (i in [0,16))
        int x = blockIdx.x;
        int per = (int)gridDim.x >> 3;        // 136/8 = 17
        x = (x & 7) * per + (x >> 3);
        int a = (int)sqrtf(2.f * (float)x + 1.f);
        if (a > 15) a = 15;
        while (a < 15 && ((a + 1) * (a + 2) / 2) <= x) ++a;
        while (a > 0 && (a * (a + 1) / 2) > x) --a;
        mblk = a;
        nblk = x - a * (a + 1) / 2;
    } else if (SWIZ == 7) {
        int glin = (int)blockIdx.z * 128 + (int)blockIdx.y * 8 + (int)blockIdx.x;
        int xcd = glin & 7;
        int s   = glin >> 3;                  // [0,64) per xcd
        z = xcd >> 1;                         // batch owned by this xcd pair
        int h  = xcd & 1;
        int jm = s & 7;
        nblk   = s >> 3;                      // [0,8)
        mblk   = (jm & 1) ? (15 - h - (jm >> 1) * 2) : ((jm >> 1) * 2 + h);
    } else {
        mblk = blockIdx.y;
        nblk = blockIdx.x;
    }
    int m0 = mblk * 128;
    int n0 = nblk * 128;

    const unsigned short* Ab = A + (size_t)z * aStride;
    const unsigned short* Bb = B + (size_t)z * bStride;

    __shared__ __align__(16) char lds[65536];   // 2 x [A 16K | B 16K]

    int tid  = threadIdx.x;
    int lane = tid & 63, wid = tid >> 6;
    int wm = (wid & 1) * 64, wn = (wid >> 1) * 64;
    int fr = lane & 15, fq = lane >> 4;
    int sw0 = ((fq    ) ^ (fr & 7)) * 16;
    int sw1 = ((fq ^ 4) ^ (fr & 7)) * 16;

    int rS = tid >> 3;                       // 0..31
    int cS = ((tid & 7) ^ (rS & 7)) * 8;     // swizzled source chunk (k elems)

    int kend = KLIMIT ? min(K, m0 + 128) : K;
    int NT = kend >> 6;                      // >= 1 at all call sites

    f32x4 acc[4][4];
#pragma unroll
    for (int i = 0; i < 4; ++i)
#pragma unroll
    for (int j = 0; j < 4; ++j) acc[i][j] = f32x4{0.f, 0.f, 0.f, 0.f};

    auto STAGE = [&](int kt) {               // 8 gld_lds per thread
        char* dst = lds + (kt & 1) * 32768;
        const unsigned short* Asrc = Ab; int koff = kt << 6; int ldax = lda;
        if (AMODE == 2 && koff >= ksplit) { Asrc = A2; koff -= ksplit; ldax = lda2; }
        const unsigned short* pa = Asrc + (size_t)(m0 + rS) * ldax + koff + cS;
        const unsigned short* pb = Bb   + (size_t)(n0 + rS) * ldb + (kt << 6) + cS;
#pragma unroll
        for (int u = 0; u < 4; ++u)
            gld_lds16(pa + (size_t)(32 * u) * ldax, dst + u * 4096 + tid * 16);
#pragma unroll
        for (int u = 0; u < 4; ++u)
            gld_lds16(pb + (size_t)(32 * u) * ldb, dst + 16384 + u * 4096 + tid * 16);
    };

    STAGE(0);
    for (int t = 0; t < NT; ++t) {
        if (t + 1 < NT) {
            STAGE(t + 1);                    // 16 outstanding; wait oldest 8
            asm volatile("s_waitcnt vmcnt(8)" ::: "memory");
        } else {
            asm volatile("s_waitcnt vmcnt(0)" ::: "memory");
        }
        __builtin_amdgcn_s_barrier();        // all waves' tile-t loads landed
        __builtin_amdgcn_sched_barrier(0);
        const char* AsB = (const char*)lds + (t & 1) * 32768;
        const char* BsB = AsB + 16384;
#pragma unroll
        for (int kh = 0; kh < 2; ++kh) {
            int sw = kh ? sw1 : sw0;
            short8 a[4], b[4];
#pragma unroll
            for (int i = 0; i < 4; ++i)
                a[i] = *(const short8*)(AsB + (wm + i * 16 + fr) * 128 + sw);
#pragma unroll
            for (int j = 0; j < 4; ++j)
                b[j] = *(const short8*)(BsB + (wn + j * 16 + fr) * 128 + sw);
            __builtin_amdgcn_s_setprio(1);
#pragma unroll
            for (int i = 0; i < 4; ++i)
#pragma unroll
            for (int j = 0; j < 4; ++j)
                acc[i][j] = __builtin_amdgcn_mfma_f32_16x16x32_bf16(a[i], b[j], acc[i][j], 0, 0, 0);
            __builtin_amdgcn_s_setprio(0);
        }
        __builtin_amdgcn_s_barrier();        // WAR: next iter stages this buf
        __builtin_amdgcn_sched_barrier(0);
        asm volatile("" ::: "memory");
    }

    // epilogue: C/D layout col = lane&15, row = (lane>>4)*4 + reg [m89/m91]
    if (EPI == 6) {
        unsigned short* Cz = (unsigned short*)C + (size_t)z * cStride;
        float* rs = const_cast<float*>(bias) + z * biasStride;
#pragma unroll
        for (int i = 0; i < 4; ++i)
#pragma unroll
        for (int r = 0; r < 4; ++r) {
            int row = m0 + wm + i * 16 + fq * 4 + r;
            float s = 0.f;
#pragma unroll
            for (int j = 0; j < 4; ++j) {
                int col = n0 + wn + j * 16 + fr;
                float e = (col <= row) ? __expf(acc[i][j][r] * scale - 16.f) : 0.f;
                s += e;
                Cz[(size_t)row * ldc + col] = f32_to_bf16(e);
            }
            s += __shfl_xor(s, 1);
            s += __shfl_xor(s, 2);
            s += __shfl_xor(s, 4);
            s += __shfl_xor(s, 8);      // reduced over the 16 fr-lanes
            if (fr == 0) atomicAdd(&rs[row], s);
        }
    } else if (EPI == 4) {
        unsigned short* Cz = (unsigned short*)C + (size_t)z * cStride;
#pragma unroll
        for (int i = 0; i < 4; ++i)
#pragma unroll
        for (int r = 0; r < 4; ++r) {
            int row = m0 + wm + i * 16 + fq * 4 + r;
            float inv = 1.f / bias[z * biasStride + row];
#pragma unroll
            for (int j = 0; j < 4; ++j) {
                int col = n0 + wn + j * 16 + fr;
                Cz[(size_t)row * ldc + col] = f32_to_bf16(acc[i][j][r] * inv);
            }
        }
    } else {
#pragma unroll
        for (int i = 0; i < 4; ++i)
#pragma unroll
        for (int j = 0; j < 4; ++j)
#pragma unroll
        for (int r = 0; r < 4; ++r) {
            int row = m0 + wm + i * 16 + fq * 4 + r;
            int col = n0 + wn + j * 16 + fr;
            float v = acc[i][j][r];
            if (EPI == 2) {
                v += bias[col];
                v = v > 0.f ? v : 0.f;
                ((unsigned short*)C + (size_t)z * cStride)[(size_t)row * ldc + col] = f32_to_bf16(v);
            } else {   // 3
                ((float*)C + (size_t)z * cStride)[(size_t)row * ldc + col] = v + bias[col];
            }
        }
    }
}

// ---------------------------------------------------------------------------
// prep (R6, measured good): 64x64 transpose tiles, f32x4 loads / short4
// stores; 32-elems/thread xb convert. 2564 blocks.
// zones: [0,1024) xb | [1024,1792) Wqkv^T | [1792,2304) W1^T |
//        [2304,2560) W2^T | [2560,2564) rsum zero
// ---------------------------------------------------------------------------
__device__ __forceinline__ void transpose_tile64(const float* __restrict__ in,
                                                 unsigned short* __restrict__ out,
                                                 int rows, int cols, int bx, int by, int tid)
{
    __shared__ float t[64][65];
    int tx = tid & 15, ty = tid >> 4;   // 16 x 16
    int r0 = by * 64, c0 = bx * 64;
#pragma unroll
    for (int i = 0; i < 4; ++i) {
        f32x4 v = *(const f32x4*)(in + (size_t)(r0 + ty + i * 16) * cols + c0 + tx * 4);
#pragma unroll
        for (int j = 0; j < 4; ++j) t[ty + i * 16][tx * 4 + j] = v[j];
    }
    __syncthreads();
#pragma unroll
    for (int i = 0; i < 4; ++i) {
        union { short4v s; unsigned short u[4]; } o;
#pragma unroll
        for (int j = 0; j < 4; ++j) o.u[j] = f32_to_bf16(t[tx * 4 + j][ty + i * 16]);
        *(short4v*)(out + (size_t)(c0 + ty + i * 16) * rows + r0 + tx * 4) = o.s;
    }
}

__global__ __launch_bounds__(256)
void prep_kernel(const float* __restrict__ x,
                 const float* __restrict__ Wq, const float* __restrict__ Wk,
                 const float* __restrict__ Wv, const float* __restrict__ W1,
                 const float* __restrict__ W2,
                 unsigned short* __restrict__ xb, unsigned short* __restrict__ WT,
                 unsigned short* __restrict__ W1T, unsigned short* __restrict__ W2T,
                 float* __restrict__ rsum)
{
    int idx = blockIdx.x;
    int tid = threadIdx.x;
    if (idx < 1024) {
#pragma unroll
        for (int it = 0; it < 4; ++it) {
            size_t i = ((size_t)idx * 4 + it) * 2048 + (size_t)tid * 8;
            *(short8*)(xb + i) = load8_f32_as_bf16(x + i);
        }
    } else if (idx < 1792) {
        int t = idx - 1024;
        int w = t >> 8; t &= 255;
        const float* in = w == 0 ? Wq : (w == 1 ? Wk : Wv);
        transpose_tile64(in, WT + (size_t)w * 1024 * 1024, 1024, 1024,
                         t & 15, t >> 4, tid);
    } else if (idx < 2304) {
        int t = idx - 1792;                  // 512 tiles: 32 row-tiles x 16
        transpose_tile64(W1, W1T, 2048, 1024, t & 15, t >> 4, tid);
    } else if (idx < 2560) {
        int t = idx - 2304;                  // 256 tiles
        transpose_tile64(W2, W2T, 1024, 1024, t & 15, t >> 4, tid);
    } else {
        int t = idx - 2560;
        f32x4 zero = {0.f, 0.f, 0.f, 0.f};
        float* p = rsum + ((size_t)t * 256 + tid) * 8;
        *(f32x4*)p = zero;
        *(f32x4*)(p + 4) = zero;
    }
}

// ---------------------------------------------------------------------------
extern "C" void kernel_launch(void* const* d_in, const int* in_sizes, int n_in,
                              void* d_out, int out_size, void* d_ws, size_t ws_size,
                              hipStream_t stream)
{
    const float* x  = (const float*)d_in[0];   // [8192,1024]
    const float* Wq = (const float*)d_in[1];
    const float* Wk = (const float*)d_in[2];
    const float* Wv = (const float*)d_in[3];
    const float* W1 = (const float*)d_in[4];   // [2048,1024]
    const float* b1 = (const float*)d_in[5];
    const float* W2 = (const float*)d_in[6];   // [1024,1024]
    const float* b2 = (const float*)d_in[7];
    float* out = (float*)d_out;                // [8192,1024] fp32

    size_t off = 0;
    auto alloc = [&](size_t bytes) {
        char* r = (char*)d_ws + off;
        off += (bytes + 255) & ~(size_t)255;
        return r;
    };
    const size_t TOK = (size_t)8192 * 1024;    // tokens x dim
    unsigned short* WT   = (unsigned short*)alloc((size_t)3072 * 1024 * 2);
    unsigned short* W1T  = (unsigned short*)alloc((size_t)1024 * 2048 * 2);
    unsigned short* W2T  = (unsigned short*)alloc((size_t)1024 * 1024 * 2);
    unsigned short* xb   = (unsigned short*)alloc(TOK * 2);
    unsigned short* vT   = (unsigned short*)alloc((size_t)1024 * 8192 * 2); // [d][b*2048+s]
    unsigned short* attn = (unsigned short*)alloc(TOK * 2);
    float*          rsum = (float*)         alloc((size_t)4 * 2048 * 4);
    unsigned short* q    = (unsigned short*)alloc(TOK * 2);
    unsigned short* k    = (unsigned short*)alloc(TOK * 2);
    unsigned short* S    = (unsigned short*)alloc((size_t)4 * 2048 * 2048 * 2);
    unsigned short* h1   = S;                  // S dead after PV; MLP1 out aliases it
    // peak ws use: ~131 MB

    // prep: xb, WT, W1T, W2T, rsum=0 in one launch (2564 blocks, vectorized)
    prep_kernel<<<2564, 256, 0, stream>>>(x, Wq, Wk, Wv, W1, W2, xb, WT, W1T, W2T, rsum);

    // fused q,k,vT (z<2: q,k = xb @ Wqk^T m-chunked; z==2: vT = WvT @ xb^T
    // n-chunked). 1536 blocks = 6/CU. Measured 52.3 us / 966 TF.
    gemm128<0, 0, 6, false, 128><<<dim3(8, 64, 3), 256, 0, stream>>>(
        xb, nullptr, 1024, 0, 0, WT, 1024, q, 1024, 1024,
        0, (long)1024 * 1024, (long)TOK, nullptr, 0, 0.f, vT, 8192);

    // scores+softmax fused, 128-row m-tiles: P = exp(q@k^T/32 - 16) (causal),
    // rowsums -> rsum. Triangular 136/z x 4, xcd pre-permute. DOUBLE-BUFFERED.
    gemmdb<0, 6, 5, false><<<dim3(136, 1, 4), 256, 0, stream>>>(
        q, nullptr, 1024, 0, 0, k, 1024, S, 2048, 1024,
        (long)2048 * 1024, (long)2048 * 1024, (long)2048 * 2048, rsum, 2048, 0.03125f);

    // attn = (P @ v) / rsum[row]  (kend = m0+128; SWIZ=7 z-per-xcd-pair,
    // balanced m-sets, grid (8,16,4)). DOUBLE-BUFFERED.
    gemmdb<0, 4, 7, true><<<dim3(8, 16, 4), 256, 0, stream>>>(
        S, nullptr, 2048, 0, 0, vT, 8192, attn, 1024, 2048,
        (long)2048 * 2048, (long)2048, (long)2048 * 1024, rsum, 2048, 0.f);

    // MLP1: h1 = relu([attn | x] @ W1 + b1), split-A concat trick.
    // 64 m-tiles x 8 n-blocks = 512 blocks, K=2048. DOUBLE-BUFFERED.
    gemmdb<2, 2, 1, false><<<dim3(8, 64, 1), 256, 0, stream>>>(
        attn, xb, 1024, 1024, 1024, W1T, 2048, h1, 1024, 2048,
        0, 0, 0, b1, 0, 0.f);

    // MLP2: out = h1 @ W2 + b2 (fp32 to d_out), 512 blocks. DOUBLE-BUFFERED.
    gemmdb<0, 3, 1, false><<<dim3(8, 64, 1), 256, 0, stream>>>(
        h1, nullptr, 1024, 0, 0, W2T, 1024, out, 1024, 1024,
        0, 0, 0, b2, 0, 0.f);
}